// Round 11
// baseline (48.477 us; speedup 1.0000x reference)
//
#include <hip/hip_runtime.h>
#include <math.h>

#define N_ELEM 8388608
#define MLE_EPS 1e-5f
#define BLOCK 256
#define NBLOCKS 2048          // 524288 threads x 16 elements

// Abramowitz-Stegun 7.1.26 erfc: abs error <= 1.5e-7.
__device__ __forceinline__ float fast_erfc(float x) {
    float ax = __builtin_fabsf(x);
    float t  = __builtin_amdgcn_rcpf(__builtin_fmaf(0.3275911f, ax, 1.0f));
    float p  = 1.061405429f;
    p = __builtin_fmaf(p, t, -1.453152027f);
    p = __builtin_fmaf(p, t,  1.421413741f);
    p = __builtin_fmaf(p, t, -0.284496736f);
    p = __builtin_fmaf(p, t,  0.254829592f);
    p = p * t;
    float e = __expf(-ax * ax);
    float r = p * e;
    return (x < 0.0f) ? (2.0f - r) : r;
}

__device__ __forceinline__ float mle_elem(float mu, float ls, float t, int al) {
    const float inv_sqrt2    = 0.7071067811865476f;
    const float half_log_2pi = 0.9189385332046727f;

    float lx        = __logf(t + MLE_EPS);
    float inv_sigma = __expf(-ls);
    float d         = lx - mu;
    float w         = d * inv_sigma;
    float z         = w * inv_sqrt2;
    float loss_alive = -__logf(__builtin_fmaf(0.5f, fast_erfc(z), MLE_EPS));
    float loss_dead  = lx + ls + half_log_2pi + 0.5f * w * w;
    return al ? loss_alive : loss_dead;
}

// Pair-dense layout (R10), single fused kernel: each block finishes with ONE
// relaxed device-scope atomicAdd of its partial/N to out[0]. This is NOT
// R3's acq-rel pattern (no fences, no cross-block reads) -> no L2
// writeback/invalidate storm; the 2048 atomics overlap with other blocks'
// compute. Ordering wobble ~1e-6 << 0.115 threshold.
__global__ __launch_bounds__(BLOCK, 4) void mle_fused_kernel(
    const float* __restrict__ pred,
    const float* __restrict__ tte,
    const int*   __restrict__ alive,
    float* __restrict__ out,
    int n2)   // number of pairs (N/2 = 4M)
{
    const float4* __restrict__ p4 = (const float4*)pred;
    const float2* __restrict__ t2 = (const float2*)tte;
    const int2*   __restrict__ a2 = (const int2*)alive;

    const int g  = blockIdx.x * BLOCK + threadIdx.x;
    const int NT = NBLOCKS * BLOCK;               // 524288
    float acc = 0.0f;

    if (n2 == 8 * NT) {                           // exact fit (N = 8388608)
        #pragma unroll
        for (int r = 0; r < 8; ++r) {
            const int j = g + r * NT;
            float4 p = p4[j];
            float2 t = t2[j];
            int2   a = a2[j];
            acc += mle_elem(p.x, p.y, t.x, a.x);
            acc += mle_elem(p.z, p.w, t.y, a.y);
        }
    } else {
        for (int j = g; j < n2; j += NT) {
            float4 p = p4[j];
            float2 t = t2[j];
            int2   a = a2[j];
            acc += mle_elem(p.x, p.y, t.x, a.x);
            acc += mle_elem(p.z, p.w, t.y, a.y);
        }
    }

    #pragma unroll
    for (int off = 32; off > 0; off >>= 1)
        acc += __shfl_down(acc, off);

    __shared__ float wsum[BLOCK / 64];
    if ((threadIdx.x & 63) == 0) wsum[threadIdx.x >> 6] = acc;
    __syncthreads();
    if (threadIdx.x == 0) {
        float s = 0.0f;
        #pragma unroll
        for (int w = 0; w < BLOCK / 64; ++w) s += wsum[w];
        atomicAdd(out, s * (1.0f / (float)N_ELEM));
    }
}

extern "C" void kernel_launch(void* const* d_in, const int* in_sizes, int n_in,
                              void* d_out, int out_size, void* d_ws, size_t ws_size,
                              hipStream_t stream) {
    const float* pred  = (const float*)d_in[0];
    const float* tte   = (const float*)d_in[1];
    const int*   alive = (const int*)d_in[2];
    float* out = (float*)d_out;

    const int n  = in_sizes[1];
    const int n2 = n >> 1;   // 4M pairs

    hipMemsetAsync(out, 0, sizeof(float), stream);   // self-contained each call
    mle_fused_kernel<<<NBLOCKS, BLOCK, 0, stream>>>(pred, tte, alive, out, n2);
}

// Round 12
// 26.470 us; speedup vs baseline: 1.8314x; 1.8314x over previous
//
#include <hip/hip_runtime.h>
#include <math.h>

#define N_ELEM 8388608
#define MLE_EPS 1e-5f
#define BLOCK 256
#define NBLOCKS 2048          // 524288 threads x 16 elements

typedef float f32x4 __attribute__((ext_vector_type(4)));
typedef float f32x2 __attribute__((ext_vector_type(2)));
typedef int   i32x2 __attribute__((ext_vector_type(2)));

// Abramowitz-Stegun 7.1.26 erfc: abs error <= 1.5e-7.
__device__ __forceinline__ float fast_erfc(float x) {
    float ax = __builtin_fabsf(x);
    float t  = __builtin_amdgcn_rcpf(__builtin_fmaf(0.3275911f, ax, 1.0f));
    float p  = 1.061405429f;
    p = __builtin_fmaf(p, t, -1.453152027f);
    p = __builtin_fmaf(p, t,  1.421413741f);
    p = __builtin_fmaf(p, t, -0.284496736f);
    p = __builtin_fmaf(p, t,  0.254829592f);
    p = p * t;
    float e = __expf(-ax * ax);
    float r = p * e;
    return (x < 0.0f) ? (2.0f - r) : r;
}

__device__ __forceinline__ float mle_elem(float mu, float ls, float t, int al) {
    const float inv_sqrt2    = 0.7071067811865476f;
    const float half_log_2pi = 0.9189385332046727f;

    float lx        = __logf(t + MLE_EPS);
    float inv_sigma = __expf(-ls);
    float d         = lx - mu;
    float w         = d * inv_sigma;
    float z         = w * inv_sqrt2;
    float loss_alive = -__logf(__builtin_fmaf(0.5f, fast_erfc(z), MLE_EPS));
    float loss_dead  = lx + ls + half_log_2pi + 0.5f * w * w;
    return al ? loss_alive : loss_dead;
}

// R10 pair-dense structure + NON-TEMPORAL loads: the timed loop re-streams
// 134 MB through the 32 MB aggregate L2 every replay (reuse lives in L3);
// nt-flagged global_loads skip L2 allocation churn for the once-read streams.
__global__ __launch_bounds__(BLOCK, 4) void mle_partial_kernel(
    const float* __restrict__ pred,
    const float* __restrict__ tte,
    const int*   __restrict__ alive,
    float* __restrict__ partials,
    int n2)   // number of pairs (N/2 = 4M)
{
    const f32x4* __restrict__ p4 = (const f32x4*)pred;
    const f32x2* __restrict__ t2 = (const f32x2*)tte;
    const i32x2* __restrict__ a2 = (const i32x2*)alive;

    const int g  = blockIdx.x * BLOCK + threadIdx.x;
    const int NT = NBLOCKS * BLOCK;               // 524288
    float acc = 0.0f;

    if (n2 == 8 * NT) {                           // exact fit (N = 8388608)
        #pragma unroll
        for (int r = 0; r < 8; ++r) {
            const int j = g + r * NT;
            f32x4 p = __builtin_nontemporal_load(&p4[j]);
            f32x2 t = __builtin_nontemporal_load(&t2[j]);
            i32x2 a = __builtin_nontemporal_load(&a2[j]);
            acc += mle_elem(p[0], p[1], t[0], a[0]);
            acc += mle_elem(p[2], p[3], t[1], a[1]);
        }
    } else {
        for (int j = g; j < n2; j += NT) {
            f32x4 p = __builtin_nontemporal_load(&p4[j]);
            f32x2 t = __builtin_nontemporal_load(&t2[j]);
            i32x2 a = __builtin_nontemporal_load(&a2[j]);
            acc += mle_elem(p[0], p[1], t[0], a[0]);
            acc += mle_elem(p[2], p[3], t[1], a[1]);
        }
    }

    #pragma unroll
    for (int off = 32; off > 0; off >>= 1)
        acc += __shfl_down(acc, off);

    __shared__ float wsum[BLOCK / 64];
    if ((threadIdx.x & 63) == 0) wsum[threadIdx.x >> 6] = acc;
    __syncthreads();
    if (threadIdx.x == 0) {
        float s = 0.0f;
        #pragma unroll
        for (int w = 0; w < BLOCK / 64; ++w) s += wsum[w];
        partials[blockIdx.x] = s;
    }
}

__global__ __launch_bounds__(BLOCK) void mle_final_kernel(
    const float4* __restrict__ partials4, float* __restrict__ out)
{
    float acc = 0.0f;
    #pragma unroll
    for (int k = 0; k < 2; ++k) {
        float4 v = partials4[threadIdx.x + k * BLOCK];
        acc += (v.x + v.y) + (v.z + v.w);
    }

    #pragma unroll
    for (int off = 32; off > 0; off >>= 1)
        acc += __shfl_down(acc, off);

    __shared__ float wsum[BLOCK / 64];
    if ((threadIdx.x & 63) == 0) wsum[threadIdx.x >> 6] = acc;
    __syncthreads();
    if (threadIdx.x == 0) {
        float s = 0.0f;
        #pragma unroll
        for (int w = 0; w < BLOCK / 64; ++w) s += wsum[w];
        out[0] = s / (float)N_ELEM;
    }
}

extern "C" void kernel_launch(void* const* d_in, const int* in_sizes, int n_in,
                              void* d_out, int out_size, void* d_ws, size_t ws_size,
                              hipStream_t stream) {
    const float* pred  = (const float*)d_in[0];
    const float* tte   = (const float*)d_in[1];
    const int*   alive = (const int*)d_in[2];
    float* out = (float*)d_out;
    float* partials = (float*)d_ws;

    const int n  = in_sizes[1];
    const int n2 = n >> 1;   // 4M pairs

    mle_partial_kernel<<<NBLOCKS, BLOCK, 0, stream>>>(pred, tte, alive, partials, n2);
    mle_final_kernel<<<1, BLOCK, 0, stream>>>((const float4*)partials, out);
}